// Round 3
// baseline (128906.812 us; speedup 1.0000x reference)
//
#include <hip/hip_runtime.h>
#include <hip/hip_bf16.h>

#define NB 64
#define NT 600
#define NTC 50
#define NH 400
#define NKATT 10
#define NALPHA 60
#define NOUT 121

typedef unsigned short u16;
typedef _Float16 f16x2 __attribute__((ext_vector_type(2)));
typedef _Float16 f16x4 __attribute__((ext_vector_type(4)));
typedef _Float16 f16x8 __attribute__((ext_vector_type(8)));

#if defined(__has_builtin)
#if __has_builtin(__builtin_amdgcn_fdot2)
#define FDOT2(a,b,c) __builtin_amdgcn_fdot2((a),(b),(c),false)
#endif
#endif
#ifndef FDOT2
#define FDOT2(a,b,c) ((c) + (float)(a)[0]*(float)(b)[0] + (float)(a)[1]*(float)(b)[1])
#endif

// Padded fused-K sizes (pairs): K1=512->256, K2=896->448, K3=1280->640. Rows padded 1600->1664.
#define ROWSP 1664

// Ring-buffered cross-block state (floats). All rings depth 4.
#define H1R 0            // [4][NB][NH]
#define H2R 102400       // [4][NB][NH]
#define H3R 204800       // [4][NB][NH]
#define WINR 307200      // [4][NB][NALPHA]
#define ST_FLOATS 322560
#define SLOT_H 25600
#define SLOT_W 3840

// Driver smem layout (bytes) — the largest role.
#define OFD_WATT 0       // 25600 persistent W_att f16 pairs
#define OFD_INB  25600   // 2 x 8192: double-buffered [8][256] pairs (h1 | win | x | 0-tail)
#define OFD_ACCS 41984   // 4608
#define OFD_AB   46592   // 960
#define OFD_PHI  47552   // 1600
#define OFD_KAP  49152   // 320
#define OFD_CHS  49472   // 1600
#define OFD_LEN  51072   // 32
#define OFD_C1   51104   // 13312 = 13*256 floats (c1 for all 400 rows x 8 batches)
#define SMEM_TOTAL 64416
// Team smem: inb @0 (<=20480 = [8][640]), accS @20480 (4608), c @25088 (1024)
#define OFT_ACCS 20480
#define OFT_C    25088
// Head smem: zb @0 (9600), zv @9600 (1936)

__device__ __align__(16) f16x2 g_WT1[256 * ROWSP];
__device__ __align__(16) f16x2 g_WT2[448 * ROWSP];
__device__ __align__(16) f16x2 g_WT3[640 * ROWSP];
__device__ __align__(16) f16x2 g_WG8[150 * 128 * 4];  // [k8][r][j] f16x2 pairs
__device__ __align__(16) f16x2 g_WattP[200 * 32];
__device__ __align__(16) float g_fb1[ROWSP], g_fb2[ROWSP], g_fb3[ROWSP];
__device__ float g_batt[30], g_bgmm[121];
__device__ __align__(16) float g_inp[115200];
__device__ __align__(16) float g_state[ST_FLOATS];
__device__ unsigned int g_cnt[8 * 4 * 32];   // [bg][cid], one cacheline per counter
__device__ int g_isf32;

// Counters (per bg). Semantics: value after step t fully done =
//   CNT_A: t+1   (driver: h1(t) AND win(t) published)
//   CNT_B: 13(t+1) (LSTM2 team: h2(t) published by all 13)
//   CNT_C: 13(t+1) (LSTM3 team: h3(t) published by all 13)
//   CNT_D: 2(t+1)  (heads: out(t) complete -> done READING h1/h2/h3(t))
// Safety (rings depth 4): driver at step t writes h1(t+1)/win over slots holding
// step t-3. Throttle CNT_D >= 2(t-2) <=> heads done out(t-3) => CNT_C >= 13(t-2)
// => LSTM3 done t-3 (read h1/h2/win/h3 of t-3) => CNT_B >= 13(t-2) => LSTM2 done
// t-3 (read h1/win(t-3)). So ONE check covers every ring. Teams never pass the
// driver (gated on CNT_A), so no other throttle is needed.
#define CNT_A 0
#define CNT_B 1
#define CNT_C 2
#define CNT_D 3

__device__ __forceinline__ float bf2f(u16 v) {
    union { unsigned int u; float f; } t; t.u = ((unsigned int)v) << 16; return t.f;
}
__device__ __forceinline__ u16 f2bf(float f) {
    union { float ff; unsigned int u; } t; t.ff = f;
    unsigned int lsb = (t.u >> 16) & 1u;
    t.u += 0x7fffu + lsb;
    return (u16)(t.u >> 16);
}
__device__ __forceinline__ float sigm(float x) { return 1.f / (1.f + expf(-x)); }
__device__ __forceinline__ f16x2 packpair(float a, float b) {
    f16x2 r; r[0] = (_Float16)a; r[1] = (_Float16)b; return r;
}

// ---- agent-scope (cross-XCD coherent, LLC-direct) state accessors ----
__device__ __forceinline__ void st_agent(float* p, float v) {
    __hip_atomic_store(p, v, __ATOMIC_RELAXED, __HIP_MEMORY_SCOPE_AGENT);
}
__device__ __forceinline__ float2 ld2_agent(const float* p) {
    unsigned long long u = __hip_atomic_load((const unsigned long long*)p,
                                             __ATOMIC_RELAXED, __HIP_MEMORY_SCOPE_AGENT);
    union { unsigned long long u; float2 f; } t; t.u = u; return t.f;
}
__device__ __forceinline__ unsigned ld_cnt(int bg, int cid) {
    return __hip_atomic_load(&g_cnt[(bg * 4 + cid) * 32], __ATOMIC_RELAXED, __HIP_MEMORY_SCOPE_AGENT);
}
// Precondition: a __syncthreads() (vmcnt-draining) precedes every bump in program order.
__device__ __forceinline__ void cnt_bump(int bg, int cid) {
    if (threadIdx.x == 0)
        __hip_atomic_fetch_add(&g_cnt[(bg * 4 + cid) * 32], 1u, __ATOMIC_RELAXED, __HIP_MEMORY_SCOPE_AGENT);
}
__device__ __forceinline__ void cnt_wait(int bg, int cid, unsigned tgt) {
    if (threadIdx.x == 0 && tgt > 0) {
        while (ld_cnt(bg, cid) < tgt) __builtin_amdgcn_s_sleep(1);
    }
    __syncthreads();
}

__global__ void k_detect(const void* whh1) {
    if (threadIdx.x == 0 && blockIdx.x == 0) {
        const u16* p = (const u16*)whh1;
        int f32 = 0;
        for (int k = 0; k < 256; ++k) {
            float v = bf2f(p[2 * k]);
            if (!(fabsf(v) < 1e3f)) f32 = 1;
        }
        g_isf32 = f32;
    }
}

// Build fused/transposed/permuted f16 weights + biases; canonicalize inputs; zero state.
__global__ void k_convert(const void* inp,
                          const void* wih1, const void* bih1, const void* whh1, const void* bhh1,
                          const void* wih2, const void* bih2, const void* whh2, const void* bhh2,
                          const void* wih3, const void* bih3, const void* whh3, const void* bhh3,
                          const void* watt, const void* batt, const void* wgmm, const void* bgmm)
{
    const int gt = blockIdx.x * blockDim.x + threadIdx.x;
    const int gs = gridDim.x * blockDim.x;
    const int f32 = g_isf32;
    auto ld = [f32](const void* p, int i) -> float {
        return f32 ? ((const float*)p)[i] : bf2f(((const u16*)p)[i]);
    };
    auto w1col = [&](int kf, int row) -> float {
        if (kf < 400) return ld(whh1, row * 400 + kf);
        if (kf < 460) return ld(wih1, row * 63 + (kf - 400));
        if (kf < 463) return ld(wih1, row * 63 + 60 + (kf - 460));
        return 0.f;
    };
    auto w2col = [&](int kf, int row) -> float {
        if (kf < 400) return ld(wih2, row * 463 + 3 + kf);
        if (kf < 800) return ld(whh2, row * 400 + (kf - 400));
        if (kf < 860) return ld(wih2, row * 463 + 403 + (kf - 800));
        if (kf < 863) return ld(wih2, row * 463 + (kf - 860));
        return 0.f;
    };
    auto w3col = [&](int kf, int row) -> float {
        if (kf < 400)  return ld(wih3, row * 863 + 3 + kf);
        if (kf < 800)  return ld(wih3, row * 863 + 403 + (kf - 400));
        if (kf < 1200) return ld(whh3, row * 400 + (kf - 800));
        if (kf < 1260) return ld(wih3, row * 863 + 803 + (kf - 1200));
        if (kf < 1263) return ld(wih3, row * 863 + (kf - 1260));
        return 0.f;
    };
    for (int i = gt; i < 256 * ROWSP; i += gs) {
        int k2 = i / ROWSP, rp = i % ROWSP;
        int j = rp >> 2, g = rp & 3;
        float a = 0.f, b = 0.f;
        if (j < 400) { int row = g * 400 + j; a = w1col(2 * k2, row); b = w1col(2 * k2 + 1, row); }
        g_WT1[i] = packpair(a, b);
    }
    for (int i = gt; i < 448 * ROWSP; i += gs) {
        int k2 = i / ROWSP, rp = i % ROWSP;
        int j = rp >> 2, g = rp & 3;
        float a = 0.f, b = 0.f;
        if (j < 400) { int row = g * 400 + j; a = w2col(2 * k2, row); b = w2col(2 * k2 + 1, row); }
        g_WT2[i] = packpair(a, b);
    }
    for (int i = gt; i < 640 * ROWSP; i += gs) {
        int k2 = i / ROWSP, rp = i % ROWSP;
        int j = rp >> 2, g = rp & 3;
        float a = 0.f, b = 0.f;
        if (j < 400) { int row = g * 400 + j; a = w3col(2 * k2, row); b = w3col(2 * k2 + 1, row); }
        g_WT3[i] = packpair(a, b);
    }
    for (int i = gt; i < ROWSP; i += gs) {
        int j = i >> 2, g = i & 3;
        float b1 = 0.f, b2 = 0.f, b3 = 0.f;
        if (j < 400) {
            int row = g * 400 + j;
            b1 = ld(bih1, row) + ld(bhh1, row);
            b2 = ld(bih2, row) + ld(bhh2, row);
            b3 = ld(bih3, row) + ld(bhh3, row);
        }
        g_fb1[i] = b1; g_fb2[i] = b2; g_fb3[i] = b3;
    }
    for (int i = gt; i < 200 * 32; i += gs) {        // W_att f16 pairs [k2][r]
        int k2 = i / 32, r = i % 32;
        float a = 0.f, b = 0.f;
        if (r < 30) { a = ld(watt, r * 400 + 2 * k2); b = ld(watt, r * 400 + 2 * k2 + 1); }
        g_WattP[i] = packpair(a, b);
    }
    for (int i = gt; i < 150 * 128 * 4; i += gs) {   // W_gmm f16x8-coalesced [k8][r][j]
        int k8 = i >> 9, rem = i & 511, r = rem >> 2, j = rem & 3;
        int kp = k8 * 4 + j;
        float a = 0.f, b = 0.f;
        if (r < 121) { a = ld(wgmm, r * 1200 + 2 * kp); b = ld(wgmm, r * 1200 + 2 * kp + 1); }
        g_WG8[i] = packpair(a, b);
    }
    for (int i = gt; i < 30; i += gs)  g_batt[i] = ld(batt, i);
    for (int i = gt; i < 121; i += gs) g_bgmm[i] = ld(bgmm, i);
    for (int i = gt; i < 115200; i += gs) g_inp[i] = ld(inp, i);
    for (int i = gt; i < ST_FLOATS; i += gs) g_state[i] = 0.f;
    for (int i = gt; i < 8 * 4 * 32; i += gs) g_cnt[i] = 0u;
}

// LSTM core: 8 waves split K in k4-groups; lane = 2 rowpairs x 8 batches.
// c-state in block-local LDS; h published to an LLC ring slot.
// DRV: additionally write h as f16 into hL (the driver's next inb buffer).
template<int KP2, bool DRV>
__device__ __forceinline__ void lstm_core(const f16x2* __restrict__ WT, const float* __restrict__ fb,
                                          float* __restrict__ cL, float* __restrict__ hdst,
                                          f16x2* hL,
                                          const f16x2* inb, float* accS, int rg, int bg, int tid)
{
    const int wv = tid >> 6, lane = tid & 63;
    const int ck4 = KP2 >> 5;
    const int k40 = wv * ck4;
    const int rbase = rg * 128 + lane * 2;
    float acc[2][8];
    #pragma unroll
    for (int r = 0; r < 2; ++r)
        #pragma unroll
        for (int b = 0; b < 8; ++b) acc[r][b] = 0.f;
    const f16x2* wp = WT + (size_t)(k40 * 4) * ROWSP + rbase;
    #pragma unroll 2
    for (int k4 = 0; k4 < ck4; ++k4) {
        f16x2 wa[4], wb[4];
        #pragma unroll
        for (int j = 0; j < 4; ++j) {
            union { f16x4 v; f16x2 p[2]; } u;
            u.v = *(const f16x4*)(wp + (size_t)j * ROWSP);
            wa[j] = u.p[0]; wb[j] = u.p[1];
        }
        #pragma unroll
        for (int b = 0; b < 8; ++b) {
            union { f16x8 v; f16x2 p[4]; } h;
            h.v = *(const f16x8*)(inb + b * KP2 + (k40 + k4) * 4);
            #pragma unroll
            for (int j = 0; j < 4; ++j) {
                acc[0][b] = FDOT2(wa[j], h.p[j], acc[0][b]);
                acc[1][b] = FDOT2(wb[j], h.p[j], acc[1][b]);
            }
        }
        wp += 4 * ROWSP;
    }
    #pragma unroll
    for (int r = 0; r < 2; ++r)
        #pragma unroll
        for (int b = 0; b < 8; ++b)
            atomicAdd(&accS[(lane * 2 + r) * 9 + b], acc[r][b]);
    __syncthreads();
    if (tid < 256) {
        int bl = tid >> 5, jj = tid & 31;
        int j = rg * 32 + jj;
        if (j < 400) {
            int rl = jj * 4;
            float gi = accS[(rl + 0) * 9 + bl] + fb[rg * 128 + rl + 0];
            float gf = accS[(rl + 1) * 9 + bl] + fb[rg * 128 + rl + 1];
            float gg = accS[(rl + 2) * 9 + bl] + fb[rg * 128 + rl + 2];
            float go = accS[(rl + 3) * 9 + bl] + fb[rg * 128 + rl + 3];
            float c = cL[bl * 32 + jj];
            float cn = sigm(gf) * c + sigm(gi) * tanhf(gg);
            cL[bl * 32 + jj] = cn;
            float hv = sigm(go) * tanhf(cn);
            st_agent(&hdst[(bg * 8 + bl) * 400 + j], hv);
            if (DRV) ((_Float16*)hL)[bl * 512 + j] = (_Float16)hv;
        }
    }
}

// Driver's full LSTM1: 13 sequential 128-row chunks (reuses lstm_core), reading inbR,
// writing h1 -> inbW (f16, for the next step's att/LSTM1) + ring (f32, for teams).
__device__ __forceinline__ void driver_lstm1(const f16x2* inbR, f16x2* inbW, float* ring,
                                             float* accS, float* c1, int bg, int tid)
{
    for (int rg = 0; rg < 13; ++rg) {
        for (int i = tid; i < 1152; i += 512) accS[i] = 0.f;
        __syncthreads();
        lstm_core<256, true>(g_WT1, g_fb1, c1 + rg * 256, ring, inbW, inbR, accS, rg, bg, tid);
        __syncthreads();
    }
}

// Attention + window + kappa (driver only; block-local LDS state). Publishes win(t) ring.
__device__ __forceinline__ void att_window_drv(const f16x2* __restrict__ watt, f16x2* inb,
                                               float* ab, float* phi, float* kap,
                                               const int* chs, const int* len,
                                               float* winring, int bg, int tid)
{
    if (tid < 240) {
        int bl = tid / 30, rr = tid - bl * 30;
        float a0 = g_batt[rr], a1 = 0.f;
        const f16x2* hp = inb + bl * 256;
        #pragma unroll 4
        for (int k2 = 0; k2 < 200; k2 += 2) {
            a0 = FDOT2(watt[(k2 + 0) * 32 + rr], hp[k2 + 0], a0);
            a1 = FDOT2(watt[(k2 + 1) * 32 + rr], hp[k2 + 1], a1);
        }
        ab[bl * 30 + rr] = expf(a0 + a1);
    }
    __syncthreads();
    if (tid < 400) {                        // phi (length-masked), uses NEW kappa
        int bl = tid / 50, u = tid - bl * 50;
        float ph = 0.f;
        if (u < len[bl]) {
            float uf = (float)u;
            for (int k = 0; k < 10; ++k) {
                float kn = kap[bl * 10 + k] + ab[bl * 30 + 20 + k];
                float d = kn - uf;
                ph += ab[bl * 30 + k] * expf(-ab[bl * 30 + 10 + k] * d * d);
            }
        }
        phi[bl * 50 + u] = ph;
    }
    __syncthreads();
    if (tid < 240) {                        // window pairs -> inb (LDS) + ring (LLC)
        int bl = tid / 30, q = tid - bl * 30;
        int a0i = 2 * q, a1i = 2 * q + 1;
        float w0 = 0.f, w1 = 0.f;
        for (int u = 0; u < NTC; ++u) {
            float pv = phi[bl * 50 + u]; int cc = chs[bl * 50 + u];
            if (cc == a0i) w0 += pv;
            if (cc == a1i) w1 += pv;
        }
        inb[bl * 256 + 200 + q] = packpair(w0, w1);
        float* wr = winring + (bg * 8 + bl) * 60;
        st_agent(wr + a0i, w0); st_agent(wr + a1i, w1);
    } else if (tid >= 256 && tid < 336) {   // kappa += dkappa
        int i = tid - 256; int bl = i / 10, k = i - bl * 10;
        kap[bl * 10 + k] += ab[bl * 30 + 20 + k];
    }
    __syncthreads();   // drains win ring stores (vmcnt) before CNT_A bump
}

// GMM output head: 4 batches per block; all rings depth 4, slot t&3.
__device__ void out_head(void* out, int t, int obid, int tid, char* smem)
{
    f16x2* zb = (f16x2*)smem;
    float* zv = (float*)(smem + 9600);
    const float* h1 = g_state + H1R + (t & 3) * SLOT_H;
    const float* h2 = g_state + H2R + (t & 3) * SLOT_H;
    const float* h3 = g_state + H3R + (t & 3) * SLOT_H;
    for (int i = tid; i < 4 * 600; i += 512) {
        int bq = i / 600, p = i % 600; int b = obid * 4 + bq;
        int kf = 2 * p;
        const float* src = (kf < 400) ? (h1 + b * 400 + kf)
                         : (kf < 800) ? (h2 + b * 400 + (kf - 400))
                                      : (h3 + b * 400 + (kf - 800));
        float2 hv = ld2_agent(src);
        zb[bq * 600 + p] = packpair(hv.x, hv.y);
    }
    __syncthreads();
    {
        int bq = tid >> 7, r = tid & 127;
        float ac0 = (r < 121) ? g_bgmm[r] : 0.f, ac1 = 0.f, ac2 = 0.f, ac3 = 0.f;
        const f16x8* zp = (const f16x8*)(zb + bq * 600);
        #pragma unroll 4
        for (int k8 = 0; k8 < 150; ++k8) {
            union { f16x8 v; f16x2 p[4]; } w, z;
            w.v = *(const f16x8*)&g_WG8[(k8 * 128 + r) * 4];
            z.v = zp[k8];
            ac0 = FDOT2(w.p[0], z.p[0], ac0);
            ac1 = FDOT2(w.p[1], z.p[1], ac1);
            ac2 = FDOT2(w.p[2], z.p[2], ac2);
            ac3 = FDOT2(w.p[3], z.p[3], ac3);
        }
        if (r < 121) zv[bq * 121 + r] = (ac0 + ac1) + (ac2 + ac3);
    }
    __syncthreads();
    if (tid < 484) {
        int bl = tid / 121, jo = tid - bl * 121;
        const float* z = zv + bl * 121;
        float val;
        if (jo < 20) {
            float m = -1e30f;
            for (int i = 0; i < 20; ++i) m = fmaxf(m, z[1 + i]);
            float s = 0.f;
            for (int i = 0; i < 20; ++i) s += expf(z[1 + i] - m);
            val = expf(z[1 + jo] - m) / s;
        } else if (jo < 60)  val = z[jo + 1];
        else if (jo < 100)   val = expf(z[jo + 1]);
        else if (jo < 120)   val = tanhf(z[jo + 1]);
        else                 val = 1.f / (1.f + expf(-z[0]));
        int idx = ((obid * 4 + bl) * NT + t) * NOUT + jo;
        if (g_isf32) ((float*)out)[idx] = val;
        else         ((u16*)out)[idx]  = f2bf(val);
    }
    __syncthreads();
}

// Persistent kernel, 232 blocks. XCD heuristic: x = bid&7.
// Per bg: 1 driver (LSTM1+att, ALL state in LDS — zero-latency recurrence),
// 13 LSTM2 blocks, 13 LSTM3 blocks, 2 head blocks, all chasing via counters/rings.
// Driver bg b sits on XCD b -> its full WT1 (1.7 MB) is L2-resident there.
// Team rg-r blocks share XCD f(r) across bgs -> weight slices cached once per XCD.
__global__ __launch_bounds__(512) void k_persist(void* out,
                                                 const int* __restrict__ cseq,
                                                 const int* __restrict__ clen)
{
    __shared__ __align__(16) char smem[SMEM_TOTAL];
    const int tid = threadIdx.x;
    const int bid = blockIdx.x;
    const int x = bid & 7, s = bid >> 3;
    int role, rg = 0, bg = 0, obid = 0;
    if (s < 8)       { role = 1; rg = x; bg = s; }
    else if (s < 13) { role = 1; int q = 5 * x + (s - 8);  rg = 8 + (q >> 3); bg = q & 7; }
    else if (s < 21) { role = 2; rg = x; bg = s - 13; }
    else if (s < 26) { role = 2; int q = 5 * x + (s - 21); rg = 8 + (q >> 3); bg = q & 7; }
    else if (s < 28) { role = 3; obid = 2 * x + (s - 26); bg = x; }
    else             { role = 0; bg = x; }

    if (role == 0) {
        // ---------------- Driver: LSTM1 + attention, fully block-local ----------------
        f16x2* wattL = (f16x2*)(smem + OFD_WATT);
        f16x2* inbA = (f16x2*)(smem + OFD_INB);            // buffer 0
        f16x2* inbB = (f16x2*)(smem + OFD_INB + 8192);     // buffer 1
        float* accS = (float*)(smem + OFD_ACCS);
        float* ab  = (float*)(smem + OFD_AB);
        float* phi = (float*)(smem + OFD_PHI);
        float* kap = (float*)(smem + OFD_KAP);
        int* chs = (int*)(smem + OFD_CHS);
        int* len = (int*)(smem + OFD_LEN);
        float* c1 = (float*)(smem + OFD_C1);

        for (int i = tid; i < 200 * 32; i += 512) wattL[i] = g_WattP[i];
        for (int i = tid; i < 2 * 8 * 256; i += 512) inbA[i] = packpair(0.f, 0.f);  // both buffers
        for (int i = tid; i < 13 * 256; i += 512) c1[i] = 0.f;
        if (tid < 80) kap[tid] = 0.f;
        for (int i = tid; i < 400; i += 512) chs[i] = cseq[(bg * 8 + i / 50) * NTC + i % 50];
        if (tid >= 480 && tid < 488) len[tid - 480] = clen[bg * 8 + (tid - 480)];
        if (tid < 16) {                                    // x(0) into read buffer (inbB)
            int bl = tid >> 1, hh = tid & 1, b = bg * 8 + bl;
            if (hh == 0) inbB[bl * 256 + 230] = packpair(g_inp[(b * NT) * 3 + 0], g_inp[(b * NT) * 3 + 1]);
            else         inbB[bl * 256 + 231] = packpair(g_inp[(b * NT) * 3 + 2], 0.f);
        }
        __syncthreads();
        // h1(0): read inbB (zeros + x(0)), write inbA + ring slot 0.
        driver_lstm1(inbB, inbA, g_state + H1R + 0 * SLOT_H, accS, c1, bg, tid);
        __syncthreads();

        for (int t = 0; t < NT; ++t) {
            f16x2* cur = (t & 1) ? inbB : inbA;    // holds h1(t)
            f16x2* nxt = (t & 1) ? inbA : inbB;
            // win(t) from h1(t); publishes win ring; ends with vmcnt-draining sync.
            att_window_drv(wattL, cur, ab, phi, kap, chs, len,
                           g_state + WINR + (t & 3) * SLOT_W, bg, tid);
            if (tid == 0) {
                if (t >= 3) {      // ring-reuse throttle (see counter proof above)
                    unsigned tgt = 2u * (unsigned)(t - 2);
                    while (ld_cnt(bg, CNT_D) < tgt) __builtin_amdgcn_s_sleep(1);
                }
                __hip_atomic_fetch_add(&g_cnt[(bg * 4 + CNT_A) * 32], 1u,
                                       __ATOMIC_RELAXED, __HIP_MEMORY_SCOPE_AGENT);
            }
            __syncthreads();
            if (t + 1 == NT) break;
            if (tid < 16) {                        // x(t+1) into cur (read buffer of next core)
                int bl = tid >> 1, hh = tid & 1, b = bg * 8 + bl;
                if (hh == 0) cur[bl * 256 + 230] = packpair(g_inp[(b * NT + t + 1) * 3 + 0], g_inp[(b * NT + t + 1) * 3 + 1]);
                else         cur[bl * 256 + 231] = packpair(g_inp[(b * NT + t + 1) * 3 + 2], 0.f);
            }
            // h1(t+1): read cur, write nxt + ring slot (t+1)&3. (First internal sync covers x-stage.)
            driver_lstm1(cur, nxt, g_state + H1R + ((t + 1) & 3) * SLOT_H, accS, c1, bg, tid);
            __syncthreads();
        }
    } else if (role == 1) {
        // ---------------- LSTM2 team (13/bg) ----------------
        f16x2* inb2 = (f16x2*)smem;                  // [8][448]: h1 | h2p | win | x | 0-tail
        float* accS = (float*)(smem + OFT_ACCS);
        float* c2   = (float*)(smem + OFT_C);
        for (int i = tid; i < 8 * 448; i += 512) inb2[i] = packpair(0.f, 0.f);
        if (tid < 256) c2[tid] = 0.f;
        __syncthreads();
        for (int t = 0; t < NT; ++t) {
            if (tid < 16) {                          // x(t)
                int bl = tid >> 1, hh = tid & 1, b = bg * 8 + bl;
                if (hh == 0) inb2[bl * 448 + 430] = packpair(g_inp[(b * NT + t) * 3 + 0], g_inp[(b * NT + t) * 3 + 1]);
                else         inb2[bl * 448 + 431] = packpair(g_inp[(b * NT + t) * 3 + 2], 0.f);
            }
            for (int i = tid; i < 1152; i += 512) accS[i] = 0.f;
            cnt_wait(bg, CNT_B, 13u * (unsigned)t);          // peers' h2(t-1)
            const float* h2s = g_state + H2R + ((t - 1) & 3) * SLOT_H;  // slot 3 = zeros at t=0
            for (int i = tid; i < 8 * 200; i += 512) {
                int bl = i / 200, p = i - bl * 200, b = bg * 8 + bl;
                float2 hv = ld2_agent(h2s + b * 400 + 2 * p);
                inb2[bl * 448 + 200 + p] = packpair(hv.x, hv.y);
            }
            cnt_wait(bg, CNT_A, (unsigned)(t + 1));          // h1(t), win(t)
            const float* h1s = g_state + H1R + (t & 3) * SLOT_H;
            const float* ws  = g_state + WINR + (t & 3) * SLOT_W;
            for (int i = tid; i < 8 * 230; i += 512) {
                int bl = i / 230, p = i - bl * 230, b = bg * 8 + bl;
                float2 hv = (p < 200) ? ld2_agent(h1s + b * 400 + 2 * p)
                                      : ld2_agent(ws + b * 60 + 2 * (p - 200));
                inb2[bl * 448 + (p < 200 ? p : 400 + (p - 200))] = packpair(hv.x, hv.y);
            }
            __syncthreads();
            lstm_core<448, false>(g_WT2, g_fb2, c2, g_state + H2R + (t & 3) * SLOT_H, nullptr,
                                  inb2, accS, rg, bg, tid);
            __syncthreads();
            cnt_bump(bg, CNT_B);
        }
    } else if (role == 2) {
        // ---------------- LSTM3 team (13/bg) ----------------
        f16x2* inb3 = (f16x2*)smem;                  // [8][640]: h1 | h2 | h3p | win | x | 0-tail
        float* accS = (float*)(smem + OFT_ACCS);
        float* c3   = (float*)(smem + OFT_C);
        for (int i = tid; i < 8 * 640; i += 512) inb3[i] = packpair(0.f, 0.f);
        if (tid < 256) c3[tid] = 0.f;
        __syncthreads();
        for (int t = 0; t < NT; ++t) {
            if (tid < 16) {                          // x(t)
                int bl = tid >> 1, hh = tid & 1, b = bg * 8 + bl;
                if (hh == 0) inb3[bl * 640 + 630] = packpair(g_inp[(b * NT + t) * 3 + 0], g_inp[(b * NT + t) * 3 + 1]);
                else         inb3[bl * 640 + 631] = packpair(g_inp[(b * NT + t) * 3 + 2], 0.f);
            }
            for (int i = tid; i < 1152; i += 512) accS[i] = 0.f;
            cnt_wait(bg, CNT_C, 13u * (unsigned)t);          // peers' h3(t-1)
            const float* h3s = g_state + H3R + ((t - 1) & 3) * SLOT_H;  // slot 3 = zeros at t=0
            for (int i = tid; i < 8 * 200; i += 512) {
                int bl = i / 200, p = i - bl * 200, b = bg * 8 + bl;
                float2 hv = ld2_agent(h3s + b * 400 + 2 * p);
                inb3[bl * 640 + 400 + p] = packpair(hv.x, hv.y);
            }
            cnt_wait(bg, CNT_B, 13u * (unsigned)(t + 1));    // h2(t) (implies h1/win(t) ready)
            const float* h1s = g_state + H1R + (t & 3) * SLOT_H;
            const float* h2s = g_state + H2R + (t & 3) * SLOT_H;
            const float* ws  = g_state + WINR + (t & 3) * SLOT_W;
            for (int i = tid; i < 8 * 430; i += 512) {
                int bl = i / 430, p = i - bl * 430, b = bg * 8 + bl;
                float2 hv; int dst;
                if (p < 200)      { hv = ld2_agent(h1s + b * 400 + 2 * p);        dst = p; }
                else if (p < 400) { hv = ld2_agent(h2s + b * 400 + 2 * (p - 200)); dst = p; }
                else              { hv = ld2_agent(ws + b * 60 + 2 * (p - 400));   dst = 600 + (p - 400); }
                inb3[bl * 640 + dst] = packpair(hv.x, hv.y);
            }
            __syncthreads();
            lstm_core<640, false>(g_WT3, g_fb3, c3, g_state + H3R + (t & 3) * SLOT_H, nullptr,
                                  inb3, accS, rg, bg, tid);
            __syncthreads();
            cnt_bump(bg, CNT_C);
        }
    } else {
        // ---------------- Heads (2/bg): output GMM ----------------
        for (int t = 0; t < NT; ++t) {
            cnt_wait(bg, CNT_C, 13u * (unsigned)(t + 1));    // h3(t) (implies h1/h2(t))
            out_head(out, t, obid, tid, smem);               // ends with __syncthreads
            cnt_bump(bg, CNT_D);                             // done READING step t
        }
    }
}

extern "C" void kernel_launch(void* const* d_in, const int* in_sizes, int n_in,
                              void* d_out, int out_size, void* d_ws, size_t ws_size,
                              hipStream_t stream)
{
    hipLaunchKernelGGL(k_detect, dim3(1), dim3(64), 0, stream, d_in[5]);  // W_hh1
    hipLaunchKernelGGL(k_convert, dim3(2048), dim3(256), 0, stream,
                       d_in[0],
                       d_in[3], d_in[4], d_in[5], d_in[6],
                       d_in[7], d_in[8], d_in[9], d_in[10],
                       d_in[11], d_in[12], d_in[13], d_in[14],
                       d_in[15], d_in[16], d_in[17], d_in[18]);
    void* outp = d_out;
    const int* cseq = (const int*)d_in[1];
    const int* clen = (const int*)d_in[2];
    void* args[] = { (void*)&outp, (void*)&cseq, (void*)&clen };
    hipLaunchCooperativeKernel((void*)k_persist, dim3(232), dim3(512), args, 0, stream);
}

// Round 4
// 24096.362 us; speedup vs baseline: 5.3496x; 5.3496x over previous
//
#include <hip/hip_runtime.h>
#include <hip/hip_bf16.h>

#define NB 64
#define NT 600
#define NTC 50
#define NH 400
#define NKATT 10
#define NALPHA 60
#define NOUT 121

typedef unsigned short u16;
typedef _Float16 f16x2 __attribute__((ext_vector_type(2)));
typedef _Float16 f16x4 __attribute__((ext_vector_type(4)));
typedef _Float16 f16x8 __attribute__((ext_vector_type(8)));

#if defined(__has_builtin)
#if __has_builtin(__builtin_amdgcn_fdot2)
#define FDOT2(a,b,c) __builtin_amdgcn_fdot2((a),(b),(c),false)
#endif
#endif
#ifndef FDOT2
#define FDOT2(a,b,c) ((c) + (float)(a)[0]*(float)(b)[0] + (float)(a)[1]*(float)(b)[1])
#endif

// Padded fused-K sizes (pairs): K1=512->256, K2=896->448, K3=1280->640. Rows padded 1600->1664.
#define ROWSP 1664

// Ring-buffered cross-block state (floats). All rings depth 4.
#define H1R 0            // [4][NB][NH]
#define H2R 102400       // [4][NB][NH]
#define H3R 204800       // [4][NB][NH]
#define WINR 307200      // [4][NB][NALPHA]
#define ST_FLOATS 322560
#define SLOT_H 25600
#define SLOT_W 3840

// T1 smem layout (bytes) — the largest role.
#define OF1_WATT 0       // 25600 persistent W_att
#define OF1_INB1 25600   // 8192  [8][256] pairs: h1(t) | win(t) | x(t+1) | 0-tail
#define OF1_ACCS 33792   // 4608
#define OF1_AB   38400   // 960
#define OF1_PHI  39360   // 1600
#define OF1_KAP  40960   // 320
#define OF1_CHS  41280   // 1600
#define OF1_LEN  42880   // 32
#define OF1_C1   42912   // 1024
#define SMEM_TOTAL 43936
// T2 smem: inb2 @0 (14336=[8][448]), accS @14336 (4608), c2 @18944 (2048, 2 slices)
// T3 smem: inb3 @0 (20480=[8][640]), accS @20480 (4608), c3 @25088 (2048, 2 slices)
// Head smem: zb @0 (9600), zv @9600 (1936)

__device__ __align__(16) f16x2 g_WT1[256 * ROWSP];
__device__ __align__(16) f16x2 g_WT2[448 * ROWSP];
__device__ __align__(16) f16x2 g_WT3[640 * ROWSP];
__device__ __align__(16) f16x2 g_WG8[150 * 128 * 4];  // [k8][r][j] f16x2 pairs
__device__ __align__(16) f16x2 g_WattP[200 * 32];
__device__ __align__(16) float g_fb1[ROWSP], g_fb2[ROWSP], g_fb3[ROWSP];
__device__ float g_batt[30], g_bgmm[121];
__device__ __align__(16) float g_inp[115200];
__device__ __align__(16) float g_state[ST_FLOATS];
__device__ unsigned int g_cnt[8 * 8 * 32];   // [bg][cid], one cacheline per counter
__device__ int g_isf32;

// Counters (per bg). Value after step t fully done:
//   CNT_A: 13(t+1)  T1: h1(t) published by all 13 slices
//   CNT_W: t+1      T1 rg0: win(t) published (implies A >= 13(t+1) and throttle passed)
//   CNT_B: 8(t+1)   T2: h2(t) published by all 8 blocks
//   CNT_C: 8(t+1)   T3: h3(t) published by all 8 blocks
//   CNT_D: 2(t+1)   heads: out(t) written (done READING h1/h2/h3(t))
// Ring safety (depth 4): T1 at step t overwrites h1(t-3) [slot (t+1)&3] and win(t-4)
// [slot t&3]. Throttle CNT_D >= 2(t-2) <=> heads done t-3 => CNT_C >= 8(t-2) => T3 done
// t-3 (read h1/h2/win/h3p of t-3) => CNT_B >= 8(t-2) => T2 done t-3 (read h1/win/h2p).
// So ONE check in T1 covers all h1/win reuse. T2's h2(t) overwrite of h2(t-4) and T3's
// h3(t) overwrite of h3(t-4): T2/T3 at step t transitively imply CNT_W >= t+1 => T1
// passed throttle at t => heads done t-3 => all readers done t-4. QED.
#define CNT_A 0
#define CNT_W 1
#define CNT_B 2
#define CNT_C 3
#define CNT_D 4

__device__ __forceinline__ float bf2f(u16 v) {
    union { unsigned int u; float f; } t; t.u = ((unsigned int)v) << 16; return t.f;
}
__device__ __forceinline__ u16 f2bf(float f) {
    union { float ff; unsigned int u; } t; t.ff = f;
    unsigned int lsb = (t.u >> 16) & 1u;
    t.u += 0x7fffu + lsb;
    return (u16)(t.u >> 16);
}
__device__ __forceinline__ float sigm(float x) { return 1.f / (1.f + expf(-x)); }
__device__ __forceinline__ f16x2 packpair(float a, float b) {
    f16x2 r; r[0] = (_Float16)a; r[1] = (_Float16)b; return r;
}

// ---- agent-scope (cross-XCD coherent, LLC-direct) state accessors ----
__device__ __forceinline__ void st_agent(float* p, float v) {
    __hip_atomic_store(p, v, __ATOMIC_RELAXED, __HIP_MEMORY_SCOPE_AGENT);
}
__device__ __forceinline__ float2 ld2_agent(const float* p) {
    unsigned long long u = __hip_atomic_load((const unsigned long long*)p,
                                             __ATOMIC_RELAXED, __HIP_MEMORY_SCOPE_AGENT);
    union { unsigned long long u; float2 f; } t; t.u = u; return t.f;
}
__device__ __forceinline__ unsigned ld_cnt(int bg, int cid) {
    return __hip_atomic_load(&g_cnt[(bg * 8 + cid) * 32], __ATOMIC_RELAXED, __HIP_MEMORY_SCOPE_AGENT);
}
// Precondition: a __syncthreads() (vmcnt-draining) precedes every bump in program order.
__device__ __forceinline__ void cnt_bump(int bg, int cid) {
    if (threadIdx.x == 0)
        __hip_atomic_fetch_add(&g_cnt[(bg * 8 + cid) * 32], 1u, __ATOMIC_RELAXED, __HIP_MEMORY_SCOPE_AGENT);
}
__device__ __forceinline__ void cnt_wait(int bg, int cid, unsigned tgt) {
    if (threadIdx.x == 0 && tgt > 0) {
        while (ld_cnt(bg, cid) < tgt) __builtin_amdgcn_s_sleep(1);
    }
    __syncthreads();
}

__global__ void k_detect(const void* whh1) {
    if (threadIdx.x == 0 && blockIdx.x == 0) {
        const u16* p = (const u16*)whh1;
        int f32 = 0;
        for (int k = 0; k < 256; ++k) {
            float v = bf2f(p[2 * k]);
            if (!(fabsf(v) < 1e3f)) f32 = 1;
        }
        g_isf32 = f32;
    }
}

// Build fused/transposed/permuted f16 weights + biases; canonicalize inputs; zero state.
__global__ void k_convert(const void* inp,
                          const void* wih1, const void* bih1, const void* whh1, const void* bhh1,
                          const void* wih2, const void* bih2, const void* whh2, const void* bhh2,
                          const void* wih3, const void* bih3, const void* whh3, const void* bhh3,
                          const void* watt, const void* batt, const void* wgmm, const void* bgmm)
{
    const int gt = blockIdx.x * blockDim.x + threadIdx.x;
    const int gs = gridDim.x * blockDim.x;
    const int f32 = g_isf32;
    auto ld = [f32](const void* p, int i) -> float {
        return f32 ? ((const float*)p)[i] : bf2f(((const u16*)p)[i]);
    };
    auto w1col = [&](int kf, int row) -> float {
        if (kf < 400) return ld(whh1, row * 400 + kf);
        if (kf < 460) return ld(wih1, row * 63 + (kf - 400));
        if (kf < 463) return ld(wih1, row * 63 + 60 + (kf - 460));
        return 0.f;
    };
    auto w2col = [&](int kf, int row) -> float {
        if (kf < 400) return ld(wih2, row * 463 + 3 + kf);
        if (kf < 800) return ld(whh2, row * 400 + (kf - 400));
        if (kf < 860) return ld(wih2, row * 463 + 403 + (kf - 800));
        if (kf < 863) return ld(wih2, row * 463 + (kf - 860));
        return 0.f;
    };
    auto w3col = [&](int kf, int row) -> float {
        if (kf < 400)  return ld(wih3, row * 863 + 3 + kf);
        if (kf < 800)  return ld(wih3, row * 863 + 403 + (kf - 400));
        if (kf < 1200) return ld(whh3, row * 400 + (kf - 800));
        if (kf < 1260) return ld(wih3, row * 863 + 803 + (kf - 1200));
        if (kf < 1263) return ld(wih3, row * 863 + (kf - 1260));
        return 0.f;
    };
    for (int i = gt; i < 256 * ROWSP; i += gs) {
        int k2 = i / ROWSP, rp = i % ROWSP;
        int j = rp >> 2, g = rp & 3;
        float a = 0.f, b = 0.f;
        if (j < 400) { int row = g * 400 + j; a = w1col(2 * k2, row); b = w1col(2 * k2 + 1, row); }
        g_WT1[i] = packpair(a, b);
    }
    for (int i = gt; i < 448 * ROWSP; i += gs) {
        int k2 = i / ROWSP, rp = i % ROWSP;
        int j = rp >> 2, g = rp & 3;
        float a = 0.f, b = 0.f;
        if (j < 400) { int row = g * 400 + j; a = w2col(2 * k2, row); b = w2col(2 * k2 + 1, row); }
        g_WT2[i] = packpair(a, b);
    }
    for (int i = gt; i < 640 * ROWSP; i += gs) {
        int k2 = i / ROWSP, rp = i % ROWSP;
        int j = rp >> 2, g = rp & 3;
        float a = 0.f, b = 0.f;
        if (j < 400) { int row = g * 400 + j; a = w3col(2 * k2, row); b = w3col(2 * k2 + 1, row); }
        g_WT3[i] = packpair(a, b);
    }
    for (int i = gt; i < ROWSP; i += gs) {
        int j = i >> 2, g = i & 3;
        float b1 = 0.f, b2 = 0.f, b3 = 0.f;
        if (j < 400) {
            int row = g * 400 + j;
            b1 = ld(bih1, row) + ld(bhh1, row);
            b2 = ld(bih2, row) + ld(bhh2, row);
            b3 = ld(bih3, row) + ld(bhh3, row);
        }
        g_fb1[i] = b1; g_fb2[i] = b2; g_fb3[i] = b3;
    }
    for (int i = gt; i < 200 * 32; i += gs) {        // W_att f16 pairs [k2][r]
        int k2 = i / 32, r = i % 32;
        float a = 0.f, b = 0.f;
        if (r < 30) { a = ld(watt, r * 400 + 2 * k2); b = ld(watt, r * 400 + 2 * k2 + 1); }
        g_WattP[i] = packpair(a, b);
    }
    for (int i = gt; i < 150 * 128 * 4; i += gs) {   // W_gmm f16x8-coalesced [k8][r][j]
        int k8 = i >> 9, rem = i & 511, r = rem >> 2, j = rem & 3;
        int kp = k8 * 4 + j;
        float a = 0.f, b = 0.f;
        if (r < 121) { a = ld(wgmm, r * 1200 + 2 * kp); b = ld(wgmm, r * 1200 + 2 * kp + 1); }
        g_WG8[i] = packpair(a, b);
    }
    for (int i = gt; i < 30; i += gs)  g_batt[i] = ld(batt, i);
    for (int i = gt; i < 121; i += gs) g_bgmm[i] = ld(bgmm, i);
    for (int i = gt; i < 115200; i += gs) g_inp[i] = ld(inp, i);
    for (int i = gt; i < ST_FLOATS; i += gs) g_state[i] = 0.f;
    for (int i = gt; i < 8 * 8 * 32; i += gs) g_cnt[i] = 0u;
}

// LSTM core: 8 waves split K in k4-groups; lane = 2 rowpairs x 8 batches.
// c-state in block-local LDS; h published to an LLC ring slot.
template<int KP2>
__device__ __forceinline__ void lstm_core(const f16x2* __restrict__ WT, const float* __restrict__ fb,
                                          float* __restrict__ cL, float* __restrict__ hdst,
                                          const f16x2* inb, float* accS, int rg, int bg, int tid)
{
    const int wv = tid >> 6, lane = tid & 63;
    const int ck4 = KP2 >> 5;
    const int k40 = wv * ck4;
    const int rbase = rg * 128 + lane * 2;
    float acc[2][8];
    #pragma unroll
    for (int r = 0; r < 2; ++r)
        #pragma unroll
        for (int b = 0; b < 8; ++b) acc[r][b] = 0.f;
    const f16x2* wp = WT + (size_t)(k40 * 4) * ROWSP + rbase;
    #pragma unroll 2
    for (int k4 = 0; k4 < ck4; ++k4) {
        f16x2 wa[4], wb[4];
        #pragma unroll
        for (int j = 0; j < 4; ++j) {
            union { f16x4 v; f16x2 p[2]; } u;
            u.v = *(const f16x4*)(wp + (size_t)j * ROWSP);
            wa[j] = u.p[0]; wb[j] = u.p[1];
        }
        #pragma unroll
        for (int b = 0; b < 8; ++b) {
            union { f16x8 v; f16x2 p[4]; } h;
            h.v = *(const f16x8*)(inb + b * KP2 + (k40 + k4) * 4);
            #pragma unroll
            for (int j = 0; j < 4; ++j) {
                acc[0][b] = FDOT2(wa[j], h.p[j], acc[0][b]);
                acc[1][b] = FDOT2(wb[j], h.p[j], acc[1][b]);
            }
        }
        wp += 4 * ROWSP;
    }
    #pragma unroll
    for (int r = 0; r < 2; ++r)
        #pragma unroll
        for (int b = 0; b < 8; ++b)
            atomicAdd(&accS[(lane * 2 + r) * 9 + b], acc[r][b]);
    __syncthreads();
    if (tid < 256) {
        int bl = tid >> 5, jj = tid & 31;
        int j = rg * 32 + jj;
        if (j < 400) {
            int rl = jj * 4;
            float gi = accS[(rl + 0) * 9 + bl] + fb[rg * 128 + rl + 0];
            float gf = accS[(rl + 1) * 9 + bl] + fb[rg * 128 + rl + 1];
            float gg = accS[(rl + 2) * 9 + bl] + fb[rg * 128 + rl + 2];
            float go = accS[(rl + 3) * 9 + bl] + fb[rg * 128 + rl + 3];
            float c = cL[bl * 32 + jj];
            float cn = sigm(gf) * c + sigm(gi) * tanhf(gg);
            cL[bl * 32 + jj] = cn;
            st_agent(&hdst[(bg * 8 + bl) * 400 + j], sigm(go) * tanhf(cn));
        }
    }
}

// Attention + window + kappa (T1; all-LDS state, identical in all 13 blocks).
// Reads h1(t) from inb[bl*256 + 0..199]; writes win pairs to inb[bl*256 + 200..229];
// pub (rg0): also publish win(t) to the LLC ring.
__device__ __forceinline__ void att_window_t1(const f16x2* __restrict__ watt, f16x2* inb,
                                              float* ab, float* phi, float* kap,
                                              const int* chs, const int* len,
                                              float* winring, bool pub, int bg, int tid)
{
    if (tid < 240) {
        int bl = tid / 30, rr = tid - bl * 30;
        float a0 = g_batt[rr], a1 = 0.f;
        const f16x2* hp = inb + bl * 256;
        #pragma unroll 4
        for (int k2 = 0; k2 < 200; k2 += 2) {
            a0 = FDOT2(watt[(k2 + 0) * 32 + rr], hp[k2 + 0], a0);
            a1 = FDOT2(watt[(k2 + 1) * 32 + rr], hp[k2 + 1], a1);
        }
        ab[bl * 30 + rr] = expf(a0 + a1);
    }
    __syncthreads();
    if (tid < 400) {                        // phi (length-masked), uses NEW kappa
        int bl = tid / 50, u = tid - bl * 50;
        float ph = 0.f;
        if (u < len[bl]) {
            float uf = (float)u;
            for (int k = 0; k < 10; ++k) {
                float kn = kap[bl * 10 + k] + ab[bl * 30 + 20 + k];
                float d = kn - uf;
                ph += ab[bl * 30 + k] * expf(-ab[bl * 30 + 10 + k] * d * d);
            }
        }
        phi[bl * 50 + u] = ph;
    }
    __syncthreads();
    if (tid < 240) {                        // window pairs -> inb (+ ring if pub)
        int bl = tid / 30, q = tid - bl * 30;
        int a0i = 2 * q, a1i = 2 * q + 1;
        float w0 = 0.f, w1 = 0.f;
        for (int u = 0; u < NTC; ++u) {
            float pv = phi[bl * 50 + u]; int cc = chs[bl * 50 + u];
            if (cc == a0i) w0 += pv;
            if (cc == a1i) w1 += pv;
        }
        inb[bl * 256 + 200 + q] = packpair(w0, w1);
        if (pub) {
            float* wr = winring + (bg * 8 + bl) * 60;
            st_agent(wr + a0i, w0); st_agent(wr + a1i, w1);
        }
    } else if (tid >= 256 && tid < 336) {   // kappa += dkappa
        int i = tid - 256; int bl = i / 10, k = i - bl * 10;
        kap[bl * 10 + k] += ab[bl * 30 + 20 + k];
    }
    __syncthreads();   // drains win ring stores (vmcnt) before CNT_W bump
}

// GMM output head: 4 batches per block; all rings depth 4, slot t&3.
__device__ void out_head(void* out, int t, int obid, int tid, char* smem)
{
    f16x2* zb = (f16x2*)smem;
    float* zv = (float*)(smem + 9600);
    const float* h1 = g_state + H1R + (t & 3) * SLOT_H;
    const float* h2 = g_state + H2R + (t & 3) * SLOT_H;
    const float* h3 = g_state + H3R + (t & 3) * SLOT_H;
    for (int i = tid; i < 4 * 600; i += 512) {
        int bq = i / 600, p = i % 600; int b = obid * 4 + bq;
        int kf = 2 * p;
        const float* src = (kf < 400) ? (h1 + b * 400 + kf)
                         : (kf < 800) ? (h2 + b * 400 + (kf - 400))
                                      : (h3 + b * 400 + (kf - 800));
        float2 hv = ld2_agent(src);
        zb[bq * 600 + p] = packpair(hv.x, hv.y);
    }
    __syncthreads();
    {
        int bq = tid >> 7, r = tid & 127;
        float ac0 = (r < 121) ? g_bgmm[r] : 0.f, ac1 = 0.f, ac2 = 0.f, ac3 = 0.f;
        const f16x8* zp = (const f16x8*)(zb + bq * 600);
        #pragma unroll 4
        for (int k8 = 0; k8 < 150; ++k8) {
            union { f16x8 v; f16x2 p[4]; } w, z;
            w.v = *(const f16x8*)&g_WG8[(k8 * 128 + r) * 4];
            z.v = zp[k8];
            ac0 = FDOT2(w.p[0], z.p[0], ac0);
            ac1 = FDOT2(w.p[1], z.p[1], ac1);
            ac2 = FDOT2(w.p[2], z.p[2], ac2);
            ac3 = FDOT2(w.p[3], z.p[3], ac3);
        }
        if (r < 121) zv[bq * 121 + r] = (ac0 + ac1) + (ac2 + ac3);
    }
    __syncthreads();
    if (tid < 484) {
        int bl = tid / 121, jo = tid - bl * 121;
        const float* z = zv + bl * 121;
        float val;
        if (jo < 20) {
            float m = -1e30f;
            for (int i = 0; i < 20; ++i) m = fmaxf(m, z[1 + i]);
            float s = 0.f;
            for (int i = 0; i < 20; ++i) s += expf(z[1 + i] - m);
            val = expf(z[1 + jo] - m) / s;
        } else if (jo < 60)  val = z[jo + 1];
        else if (jo < 100)   val = expf(z[jo + 1]);
        else if (jo < 120)   val = tanhf(z[jo + 1]);
        else                 val = 1.f / (1.f + expf(-z[0]));
        int idx = ((obid * 4 + bl) * NT + t) * NOUT + jo;
        if (g_isf32) ((float*)out)[idx] = val;
        else         ((u16*)out)[idx]  = f2bf(val);
    }
    __syncthreads();
}

// Persistent kernel, 248 blocks (31/bg x 8). XCD heuristic: x = bid&7.
// T1 (13/bg): att + LSTM1 — THE recurrence loop, one spin/step, 13-way slice-parallel.
// T2 (8/bg):  LSTM2 only (1-2 slices/block), chases via CNT_W.
// T3 (8/bg):  LSTM3 only (1-2 slices/block), chases via CNT_B.
// Heads (2/bg): GMM output after CNT_C. Throttle CNT_D>=2(t-2) in T1 covers all rings.
__global__ __launch_bounds__(512) void k_persist(void* out,
                                                 const int* __restrict__ cseq,
                                                 const int* __restrict__ clen)
{
    __shared__ __align__(16) char smem[SMEM_TOTAL];
    const int tid = threadIdx.x;
    const int bid = blockIdx.x;
    const int x = bid & 7, s = bid >> 3;
    int role, rg = 0, bg = 0, obid = 0;
    if (s < 8)       { role = 0; rg = x; bg = s; }
    else if (s < 13) { role = 0; int q = 5 * x + (s - 8); rg = 8 + (q >> 3); bg = q & 7; }
    else if (s < 21) { role = 1; rg = x; bg = s - 13; }
    else if (s < 29) { role = 2; rg = x; bg = s - 21; }
    else             { role = 3; obid = 2 * x + (s - 29); bg = x; }

    if (role == 0) {
        // ---------------- T1: attention + LSTM1 (critical loop) ----------------
        f16x2* wattL = (f16x2*)(smem + OF1_WATT);
        f16x2* inb1 = (f16x2*)(smem + OF1_INB1);
        float* accS = (float*)(smem + OF1_ACCS);
        float* ab  = (float*)(smem + OF1_AB);
        float* phi = (float*)(smem + OF1_PHI);
        float* kap = (float*)(smem + OF1_KAP);
        int* chs = (int*)(smem + OF1_CHS);
        int* len = (int*)(smem + OF1_LEN);
        float* c1 = (float*)(smem + OF1_C1);

        for (int i = tid; i < 200 * 32; i += 512) wattL[i] = g_WattP[i];
        for (int i = tid; i < 8 * 256; i += 512) inb1[i] = packpair(0.f, 0.f);
        for (int i = tid; i < 1152; i += 512) accS[i] = 0.f;
        if (tid < 80) kap[tid] = 0.f;
        if (tid >= 128 && tid < 384) c1[tid - 128] = 0.f;
        for (int i = tid; i < 400; i += 512) chs[i] = cseq[(bg * 8 + i / 50) * NTC + i % 50];
        if (tid >= 480 && tid < 488) len[tid - 480] = clen[bg * 8 + (tid - 480)];
        if (tid < 16) {                                  // x(0)
            int bl = tid >> 1, hh = tid & 1, b = bg * 8 + bl;
            if (hh == 0) inb1[bl * 256 + 230] = packpair(g_inp[(b * NT) * 3 + 0], g_inp[(b * NT) * 3 + 1]);
            else         inb1[bl * 256 + 231] = packpair(g_inp[(b * NT) * 3 + 2], 0.f);
        }
        __syncthreads();
        // LSTM1(0): publish h1(0) slice.
        lstm_core<256>(g_WT1, g_fb1, c1, g_state + H1R + 0 * SLOT_H, inb1, accS, rg, bg, tid);
        __syncthreads();
        cnt_bump(bg, CNT_A);

        for (int t = 0; t < NT; ++t) {
            // Prep independent of h1(t): x(t+1), zero accS (prev core done; safe).
            if (t + 1 < NT && tid < 16) {
                int bl = tid >> 1, hh = tid & 1, b = bg * 8 + bl;
                if (hh == 0) inb1[bl * 256 + 230] = packpair(g_inp[(b * NT + t + 1) * 3 + 0], g_inp[(b * NT + t + 1) * 3 + 1]);
                else         inb1[bl * 256 + 231] = packpair(g_inp[(b * NT + t + 1) * 3 + 2], 0.f);
            }
            for (int i = tid; i < 1152; i += 512) accS[i] = 0.f;
            // Spin: h1(t) by all 13; ring throttle (see counter proof above).
            if (tid == 0) {
                unsigned tgtA = 13u * (unsigned)(t + 1);
                while (ld_cnt(bg, CNT_A) < tgtA) __builtin_amdgcn_s_sleep(1);
                if (t >= 3) {
                    unsigned tgtD = 2u * (unsigned)(t - 2);
                    while (ld_cnt(bg, CNT_D) < tgtD) __builtin_amdgcn_s_sleep(1);
                }
            }
            __syncthreads();
            // Gather h1(t) from ring.
            const float* h1s = g_state + H1R + (t & 3) * SLOT_H;
            for (int i = tid; i < 8 * 200; i += 512) {
                int bl = i / 200, p = i - bl * 200, b = bg * 8 + bl;
                float2 hv = ld2_agent(h1s + b * 400 + 2 * p);
                inb1[bl * 256 + p] = packpair(hv.x, hv.y);
            }
            __syncthreads();
            // att + win(t) (+ ring publish by rg0); ends with vmcnt-draining sync.
            att_window_t1(wattL, inb1, ab, phi, kap, chs, len,
                          g_state + WINR + (t & 3) * SLOT_W, rg == 0, bg, tid);
            if (rg == 0) cnt_bump(bg, CNT_W);
            // LSTM1(t+1): publish h1(t+1) slice.
            if (t + 1 < NT) {
                lstm_core<256>(g_WT1, g_fb1, c1, g_state + H1R + ((t + 1) & 3) * SLOT_H,
                               inb1, accS, rg, bg, tid);
                __syncthreads();
                cnt_bump(bg, CNT_A);
            }
        }
    } else if (role == 1) {
        // ---------------- T2: LSTM2 (1-2 slices per block) ----------------
        const int nsl = (rg < 5) ? 2 : 1;
        const int sl0 = (rg < 5) ? 2 * rg : 10 + (rg - 5);
        f16x2* inb2 = (f16x2*)smem;                  // [8][448]: h1 | h2p | win | x | 0-tail
        float* accS = (float*)(smem + 14336);
        float* c2   = (float*)(smem + 18944);        // [nsl][256]
        for (int i = tid; i < 8 * 448; i += 512) inb2[i] = packpair(0.f, 0.f);
        if (tid < 512) { c2[tid] = 0.f; }            // 2*256 max
        __syncthreads();
        for (int t = 0; t < NT; ++t) {
            if (tid < 16) {                          // x(t)
                int bl = tid >> 1, hh = tid & 1, b = bg * 8 + bl;
                if (hh == 0) inb2[bl * 448 + 430] = packpair(g_inp[(b * NT + t) * 3 + 0], g_inp[(b * NT + t) * 3 + 1]);
                else         inb2[bl * 448 + 431] = packpair(g_inp[(b * NT + t) * 3 + 2], 0.f);
            }
            for (int i = tid; i < 1152; i += 512) accS[i] = 0.f;
            if (tid == 0) {
                unsigned tgtB = 8u * (unsigned)t;    // peers' h2(t-1)
                while (tgtB > 0 && ld_cnt(bg, CNT_B) < tgtB) __builtin_amdgcn_s_sleep(1);
                unsigned tgtW = (unsigned)(t + 1);   // h1(t), win(t)
                while (ld_cnt(bg, CNT_W) < tgtW) __builtin_amdgcn_s_sleep(1);
            }
            __syncthreads();
            const float* h1s = g_state + H1R + (t & 3) * SLOT_H;
            const float* h2s = g_state + H2R + ((t - 1) & 3) * SLOT_H;  // slot 3 zeros at t=0
            const float* ws  = g_state + WINR + (t & 3) * SLOT_W;
            for (int i = tid; i < 8 * 430; i += 512) {
                int bl = i / 430, p = i - bl * 430, b = bg * 8 + bl;
                float2 hv;
                if (p < 200)      hv = ld2_agent(h1s + b * 400 + 2 * p);
                else if (p < 400) hv = ld2_agent(h2s + b * 400 + 2 * (p - 200));
                else              hv = ld2_agent(ws + b * 60 + 2 * (p - 400));
                inb2[bl * 448 + p] = packpair(hv.x, hv.y);
            }
            __syncthreads();
            for (int si = 0; si < nsl; ++si) {
                if (si > 0) {
                    for (int i = tid; i < 1152; i += 512) accS[i] = 0.f;
                    __syncthreads();
                }
                lstm_core<448>(g_WT2, g_fb2, c2 + si * 256, g_state + H2R + (t & 3) * SLOT_H,
                               inb2, accS, sl0 + si, bg, tid);
                __syncthreads();
            }
            cnt_bump(bg, CNT_B);
        }
    } else if (role == 2) {
        // ---------------- T3: LSTM3 (1-2 slices per block) ----------------
        const int nsl = (rg < 5) ? 2 : 1;
        const int sl0 = (rg < 5) ? 2 * rg : 10 + (rg - 5);
        f16x2* inb3 = (f16x2*)smem;                  // [8][640]: h1 | h2 | h3p | win | x | 0-tail
        float* accS = (float*)(smem + 20480);
        float* c3   = (float*)(smem + 25088);        // [nsl][256]
        for (int i = tid; i < 8 * 640; i += 512) inb3[i] = packpair(0.f, 0.f);
        if (tid < 512) { c3[tid] = 0.f; }
        __syncthreads();
        for (int t = 0; t < NT; ++t) {
            if (tid < 16) {                          // x(t)
                int bl = tid >> 1, hh = tid & 1, b = bg * 8 + bl;
                if (hh == 0) inb3[bl * 640 + 630] = packpair(g_inp[(b * NT + t) * 3 + 0], g_inp[(b * NT + t) * 3 + 1]);
                else         inb3[bl * 640 + 631] = packpair(g_inp[(b * NT + t) * 3 + 2], 0.f);
            }
            for (int i = tid; i < 1152; i += 512) accS[i] = 0.f;
            if (tid == 0) {
                unsigned tgtC = 8u * (unsigned)t;    // peers' h3(t-1)
                while (tgtC > 0 && ld_cnt(bg, CNT_C) < tgtC) __builtin_amdgcn_s_sleep(1);
                unsigned tgtB = 8u * (unsigned)(t + 1);  // h2(t) (transitively h1/win(t))
                while (ld_cnt(bg, CNT_B) < tgtB) __builtin_amdgcn_s_sleep(1);
            }
            __syncthreads();
            const float* h1s = g_state + H1R + (t & 3) * SLOT_H;
            const float* h2s = g_state + H2R + (t & 3) * SLOT_H;
            const float* h3s = g_state + H3R + ((t - 1) & 3) * SLOT_H;  // slot 3 zeros at t=0
            const float* ws  = g_state + WINR + (t & 3) * SLOT_W;
            for (int i = tid; i < 8 * 630; i += 512) {
                int bl = i / 630, p = i - bl * 630, b = bg * 8 + bl;
                float2 hv;
                if (p < 200)      hv = ld2_agent(h1s + b * 400 + 2 * p);
                else if (p < 400) hv = ld2_agent(h2s + b * 400 + 2 * (p - 200));
                else if (p < 600) hv = ld2_agent(h3s + b * 400 + 2 * (p - 400));
                else              hv = ld2_agent(ws + b * 60 + 2 * (p - 600));
                inb3[bl * 640 + p] = packpair(hv.x, hv.y);
            }
            __syncthreads();
            for (int si = 0; si < nsl; ++si) {
                if (si > 0) {
                    for (int i = tid; i < 1152; i += 512) accS[i] = 0.f;
                    __syncthreads();
                }
                lstm_core<640>(g_WT3, g_fb3, c3 + si * 256, g_state + H3R + (t & 3) * SLOT_H,
                               inb3, accS, sl0 + si, bg, tid);
                __syncthreads();
            }
            cnt_bump(bg, CNT_C);
        }
    } else {
        // ---------------- Heads (2/bg): output GMM ----------------
        for (int t = 0; t < NT; ++t) {
            cnt_wait(bg, CNT_C, 8u * (unsigned)(t + 1));   // h3(t) (transitively h1/h2(t))
            out_head(out, t, obid, tid, smem);             // ends with __syncthreads
            cnt_bump(bg, CNT_D);                           // done READING step t
        }
    }
}

extern "C" void kernel_launch(void* const* d_in, const int* in_sizes, int n_in,
                              void* d_out, int out_size, void* d_ws, size_t ws_size,
                              hipStream_t stream)
{
    hipLaunchKernelGGL(k_detect, dim3(1), dim3(64), 0, stream, d_in[5]);  // W_hh1
    hipLaunchKernelGGL(k_convert, dim3(2048), dim3(256), 0, stream,
                       d_in[0],
                       d_in[3], d_in[4], d_in[5], d_in[6],
                       d_in[7], d_in[8], d_in[9], d_in[10],
                       d_in[11], d_in[12], d_in[13], d_in[14],
                       d_in[15], d_in[16], d_in[17], d_in[18]);
    void* outp = d_out;
    const int* cseq = (const int*)d_in[1];
    const int* clen = (const int*)d_in[2];
    void* args[] = { (void*)&outp, (void*)&cseq, (void*)&clen };
    hipLaunchCooperativeKernel((void*)k_persist, dim3(248), dim3(512), args, 0, stream);
}